// Round 6
// baseline (1744.483 us; speedup 1.0000x reference)
//
#include <hip/hip_runtime.h>
#include <math.h>

#define DIN 128
#define HID 16
#define DOUT 12
#define NMID 11

#define CPB 128        // cols per bucket (col >> 7)
#define NBMAX 800      // max coarse buckets (runtime 782)
#define EPB 2048       // edges per binning block (R12: staged flush @ 2048)
#define EPW (EPB / 4)  // edges per wave (contiguous chunk)
#define CAP 5120       // max edges per bucket in s4 LDS
#define NPB 1024       // nodes per perm-build block
#define EPAD 16        // epack tail padding (pipeline prefetch overrun <= 15)

typedef unsigned long long ull;

// non-temporal 8B load of an int2 (evict-first in L2: keeps gather table hot)
__device__ __forceinline__ int2 ldnt2(const int2* p) {
    ull v = __builtin_nontemporal_load((const ull*)p);
    return make_int2((int)(unsigned)(v & 0xffffffffull), (int)(unsigned)(v >> 32));
}

// non-temporal 16B load/store of float4 (as 2x8B)
__device__ __forceinline__ float4 ldnt4(const float4* p) {
    const ull* u = (const ull*)p;
    ull a = __builtin_nontemporal_load(u);
    ull b = __builtin_nontemporal_load(u + 1);
    float4 r;
    r.x = __uint_as_float((unsigned)(a & 0xffffffffull));
    r.y = __uint_as_float((unsigned)(a >> 32));
    r.z = __uint_as_float((unsigned)(b & 0xffffffffull));
    r.w = __uint_as_float((unsigned)(b >> 32));
    return r;
}
__device__ __forceinline__ void stnt4(float4* p, float4 v) {
    ull a = ((ull)__float_as_uint(v.y) << 32) | __float_as_uint(v.x);
    ull b = ((ull)__float_as_uint(v.w) << 32) | __float_as_uint(v.z);
    __builtin_nontemporal_store(a, (ull*)p);
    __builtin_nontemporal_store(b, ((ull*)p) + 1);
}

// exclusive scan in place over arr[0..L), 256 threads, L <= 1024
__device__ __forceinline__ void scan4(int* arr, int L, int tid, int* wtot) {
    int lane = tid & 63, wid = tid >> 6;
    int v[4]; int s = 0;
#pragma unroll
    for (int j = 0; j < 4; ++j) {
        int idx = tid * 4 + j;
        int t = (idx < L) ? arr[idx] : 0;
        v[j] = s; s += t;
    }
    int x = s;
    for (int off = 1; off < 64; off <<= 1) {
        int y = __shfl_up(x, off, 64);
        if (lane >= off) x += y;
    }
    if (lane == 63) wtot[wid] = x;
    __syncthreads();
    if (tid == 0) { int c = 0; for (int i = 0; i < 4; ++i) { int t = wtot[i]; wtot[i] = c; c += t; } }
    __syncthreads();
    int b0 = wtot[wid] + (x - s);
#pragma unroll
    for (int j = 0; j < 4; ++j) {
        int idx = tid * 4 + j;
        if (idx < L) arr[idx] = b0 + v[j];
    }
    __syncthreads();
}

// S1: per-block coarse histogram + global bucket totals.
__global__ __launch_bounds__(256)
void s1_hist(const int* __restrict__ col, int* __restrict__ H, int* __restrict__ T,
             int E, int N, int NB) {
    __shared__ int hist[NBMAX];
    int tid = threadIdx.x;
    for (int i = tid; i < NB; i += 256) hist[i] = 0;
    __syncthreads();
    long base = (long)blockIdx.x * EPB;
    for (int r = 0; r < EPB / 256; ++r) {
        long e = base + r * 256 + tid;
        if (e < E) {
            int c = col[e];
            if ((unsigned)c < (unsigned)N) atomicAdd(&hist[c >> 7], 1);
        }
    }
    __syncthreads();
    for (int i = tid; i < NB; i += 256) {
        int h = hist[i];
        H[(long)blockIdx.x * NB + i] = h;
        if (h) atomicAdd(&T[i], h);
    }
}

// S2b: exclusive scan of bucket totals -> bStart[0..NB], single block.
__global__ __launch_bounds__(1024)
void s2b_scan(const int* __restrict__ T, int* __restrict__ bStart, int NB) {
    __shared__ int wtot[16];
    int tid = threadIdx.x, lane = tid & 63, wid = tid >> 6;
    int v = (tid < NB) ? T[tid] : 0;
    int x = v;
    for (int off = 1; off < 64; off <<= 1) {
        int y = __shfl_up(x, off, 64);
        if (lane >= off) x += y;
    }
    if (lane == 63) wtot[wid] = x;
    __syncthreads();
    if (tid == 0) { int c = 0; for (int i = 0; i < 16; ++i) { int t = wtot[i]; wtot[i] = c; c += t; } }
    __syncthreads();
    int excl = wtot[wid] + x - v;
    if (tid < NB) {
        bStart[tid] = excl;
        if (tid == NB - 1) bStart[NB] = excl + v;
    }
}

// S2c: per-(block,bucket) reservation offsets. One wave per bucket.
__global__ __launch_bounds__(256)
void s2c_scan(const int* __restrict__ H, const int* __restrict__ bStart,
              int* __restrict__ O, int NB, int nblk) {
    int wv = (blockIdx.x * 256 + threadIdx.x) >> 6;
    int lane = threadIdx.x & 63;
    if (wv >= NB) return;
    int run = bStart[wv];
    for (int k0 = 0; k0 < nblk; k0 += 64) {
        int k = k0 + lane;
        int h = (k < nblk) ? H[(long)k * NB + wv] : 0;
        int x = h;
        for (int off = 1; off < 64; off <<= 1) {
            int y = __shfl_up(x, off, 64);
            if (lane >= off) x += y;
        }
        if (k < nblk) O[(long)k * NB + wv] = run + (x - h);
        run += __shfl(x, 63, 64);
    }
}

// S3 (R12): stable bin by coarse bucket. Wave-private cursors (no barriers
// in placement) + LDS staging with coalesced flush. EPB=2048 keeps LDS at
// ~35.6KB -> 4 blocks/CU. Placement arithmetic stable & deterministic.
__global__ __launch_bounds__(256)
void s3_bin(const int* __restrict__ row, const int* __restrict__ col,
            const float* __restrict__ ew, const int* __restrict__ O,
            int2* __restrict__ bins, int E, int N, int NB) {
    __shared__ int wh[4][NBMAX];       // per-wave hist -> per-wave cursor
    __shared__ int cnt[NBMAX];         // block totals -> scan -> dlt (reused)
    __shared__ int2 ldata[EPB];
    __shared__ unsigned short bdst[EPB];
    __shared__ int wtot[4];
    int tid = threadIdx.x;
    int lane = tid & 63, wid = tid >> 6;
    long base  = (long)blockIdx.x * EPB;
    long wbase = base + (long)wid * EPW;
    for (int i = tid; i < NB; i += 256) {
        wh[0][i] = 0; wh[1][i] = 0; wh[2][i] = 0; wh[3][i] = 0;
    }
    __syncthreads();
    // pass 1: per-wave histogram over the wave's contiguous EPW edges
    for (int r = 0; r < EPW / 64; ++r) {
        long e = wbase + r * 64 + lane;
        if (e < E) {
            int c = col[e];
            if ((unsigned)c < (unsigned)N) atomicAdd(&wh[wid][c >> 7], 1);
        }
    }
    __syncthreads();
    for (int i = tid; i < NB; i += 256)
        cnt[i] = wh[0][i] + wh[1][i] + wh[2][i] + wh[3][i];
    __syncthreads();
    scan4(cnt, NB, tid, wtot);         // cnt = block-local bucket starts
    for (int i = tid; i < NB; i += 256) {
        int b0 = cnt[i];
        int h0 = wh[0][i], h1 = wh[1][i], h2 = wh[2][i];
        wh[0][i] = b0;
        wh[1][i] = b0 + h0;
        wh[2][i] = b0 + h0 + h1;
        wh[3][i] = b0 + h0 + h1 + h2;
        cnt[i] = O[(long)blockIdx.x * NB + i] - b0;   // dlt (cnt reused)
    }
    __syncthreads();
    // pass 2: stable rank within wave, place into LDS. No barriers.
    ull ltm = (lane == 0) ? 0ULL : ((~0ULL) >> (64 - lane));
    for (int r = 0; r < EPW / 64; ++r) {
        long e = wbase + r * 64 + lane;
        bool valid = (e < E);
        int c = 0;
        if (valid) { c = col[e]; valid = ((unsigned)c < (unsigned)N); }
        int b = valid ? (c >> 7) : 0;
        int rw = 0; float wv = 0.f;
        if (valid) { rw = row[e]; wv = ew[e]; }
        ull peers = __ballot(valid);
        for (int bit = 0; bit < 10; ++bit) {
            ull s = __ballot(valid && ((b >> bit) & 1));
            peers &= ((b >> bit) & 1) ? s : ~s;
        }
        int rank = __popcll(peers & ltm);
        int cng  = __popcll(peers);
        int ldr  = __ffsll(peers) - 1;
        if (ldr < 0) ldr = 0;
        int lb = 0;
        if (valid && rank == 0) lb = atomicAdd(&wh[wid][b], cng);
        int lbase = __shfl(lb, ldr, 64);
        if (valid) {
            int lpos = lbase + rank;
            if ((unsigned)lpos < (unsigned)EPB) {
                ldata[lpos] = make_int2(rw | ((c & (CPB - 1)) << 17), __float_as_int(wv));
                bdst[lpos]  = (unsigned short)b;
            }
        }
    }
    __syncthreads();
    // coalesced flush: per-bucket contiguous runs
    int lenBlock = (int)((E - base < (long)EPB) ? (E - base) : (long)EPB);
    for (int p = tid; p < lenBlock; p += 256) {
        int g = p + cnt[bdst[p]];
        if ((unsigned)g < (unsigned)E) bins[g] = ldata[p];
    }
}

// S4: per-bucket stable counting sort by local col, wave-private cursors
// (no barriers in the scatter loop). Flush CSC, start[], per-col in-edge-order
// deg sums.
__global__ __launch_bounds__(256)
void s4_sort(const int* __restrict__ bStart, int2* bins,
             int* __restrict__ start, float* __restrict__ dis,
             float* __restrict__ selfw, int E, int N) {
    __shared__ int2 ldata[CAP];
    __shared__ int wh[4][CPB];         // per-wave hist -> per-wave cursor
    __shared__ int colStart[CPB + 1];
    __shared__ int wtot[4];
    int b = blockIdx.x;
    int tid = threadIdx.x;
    int lane = tid & 63, wid = tid >> 6;
    int segs = bStart[b], sege = bStart[b + 1];
    int len = sege - segs;
    if (len > CAP) len = CAP;
    if (tid < CPB) { wh[0][tid] = 0; wh[1][tid] = 0; wh[2][tid] = 0; wh[3][tid] = 0; }
    __syncthreads();
    int rounds = (len + 255) / 256;
    int chunk = rounds * 64;           // multiple of 64; 4*chunk >= len
    int ws = wid * chunk; if (ws > len) ws = len;
    int we = ws + chunk;  if (we > len) we = len;
    for (int p = ws + lane; p < we; p += 64)
        atomicAdd(&wh[wid][(bins[segs + p].x >> 17) & (CPB - 1)], 1);
    __syncthreads();
    if (tid < CPB) colStart[tid] = wh[0][tid] + wh[1][tid] + wh[2][tid] + wh[3][tid];
    __syncthreads();
    scan4(colStart, CPB, tid, wtot);
    if (tid == 0) colStart[CPB] = len;
    if (tid < CPB) {
        int b0 = colStart[tid];
        int h0 = wh[0][tid], h1 = wh[1][tid], h2 = wh[2][tid];
        wh[0][tid] = b0;
        wh[1][tid] = b0 + h0;
        wh[2][tid] = b0 + h0 + h1;
        wh[3][tid] = b0 + h0 + h1 + h2;
        int cg = b * CPB + tid;
        if (cg < N) start[cg] = segs + b0;
    }
    if (b == (int)gridDim.x - 1 && tid == 0) start[N] = sege;
    __syncthreads();
    ull ltm = (lane == 0) ? 0ULL : ((~0ULL) >> (64 - lane));
    for (int p0 = ws; p0 < we; p0 += 64) {
        int p = p0 + lane;
        bool valid = (p < we);
        int2 d = valid ? bins[segs + p] : make_int2(0, 0);
        int c = valid ? ((d.x >> 17) & (CPB - 1)) : 0;
        ull peers = __ballot(valid);
        for (int bit = 0; bit < 7; ++bit) {
            ull s = __ballot(valid && ((c >> bit) & 1));
            peers &= ((c >> bit) & 1) ? s : ~s;
        }
        int rank = __popcll(peers & ltm);
        int cng  = __popcll(peers);
        int ldr  = __ffsll(peers) - 1;
        if (ldr < 0) ldr = 0;
        int lb = 0;
        if (valid && rank == 0) lb = atomicAdd(&wh[wid][c], cng);
        int lbase = __shfl(lb, ldr, 64);
        if (valid) {
            int lpos = lbase + rank;
            if ((unsigned)lpos < (unsigned)CAP) ldata[lpos] = d;
        }
    }
    __syncthreads();
    for (int p = tid; p < len; p += 256)
        bins[segs + p] = ldata[p];
    if (tid < CPB) {
        int cg = b * CPB + tid;
        if (cg < N) {
            int s0 = colStart[tid], e0 = colStart[tid + 1];
            float dsum = 0.f;
            for (int q = s0; q < e0; ++q)
                dsum = __fadd_rn(dsum, __int_as_float(ldata[q].y));
            dsum = __fadd_rn(dsum, 1.0f);
            dis[cg] = 1.0f / __fsqrt_rn(dsum);   // == 1/np.sqrt
            selfw[cg] = 1.0f / dsum;
        }
    }
}

// ---------------------------------------------------------------------------
// Degree-sorted node permutation (scan-built).
// ---------------------------------------------------------------------------

__device__ __forceinline__ int deg_bin(const int* start, int i) {
    int d = start[i + 1] - start[i];
    return 255 - (d > 255 ? 255 : d);
}

__global__ __launch_bounds__(256)
void pd1_hist(const int* __restrict__ start, int* __restrict__ HD, int N) {
    __shared__ int hist[256];
    int tid = threadIdx.x;
    hist[tid] = 0;
    __syncthreads();
    int base = blockIdx.x * NPB;
    for (int r = 0; r < NPB / 256; ++r) {
        int i = base + r * 256 + tid;
        if (i < N) atomicAdd(&hist[deg_bin(start, i)], 1);
    }
    __syncthreads();
    HD[blockIdx.x * 256 + tid] = hist[tid];
}

__global__ __launch_bounds__(256)
void pd2a_scan(const int* __restrict__ HD, int* __restrict__ binStart, int nbk) {
    __shared__ int arr[256];
    __shared__ int wtot[4];
    int tid = threadIdx.x;
    int tot = 0;
    for (int k = 0; k < nbk; ++k) tot += HD[k * 256 + tid];
    arr[tid] = tot;
    __syncthreads();
    scan4(arr, 256, tid, wtot);
    binStart[tid] = arr[tid];
}

__global__ __launch_bounds__(256)
void pd2b_off(const int* __restrict__ HD, const int* __restrict__ binStart,
              int* __restrict__ OD, int nbk) {
    int wv = (blockIdx.x * 256 + threadIdx.x) >> 6;
    int lane = threadIdx.x & 63;
    if (wv >= 256) return;
    int run = binStart[wv];
    for (int k0 = 0; k0 < nbk; k0 += 64) {
        int k = k0 + lane;
        int h = (k < nbk) ? HD[k * 256 + wv] : 0;
        int x = h;
        for (int off = 1; off < 64; off <<= 1) {
            int y = __shfl_up(x, off, 64);
            if (lane >= off) x += y;
        }
        if (k < nbk) OD[k * 256 + wv] = run + (x - h);
        run += __shfl(x, 63, 64);
    }
}

// pd3: permutation need NOT be stable — any valid permutation leaves all
// arithmetic orders unchanged. Plain per-lane atomic fill into OD reservations.
__global__ __launch_bounds__(256)
void pd3_fill(const int* __restrict__ start, const int* __restrict__ OD,
              int* __restrict__ perm, int N) {
    __shared__ int cur[256];
    int tid = threadIdx.x;
    cur[tid] = OD[blockIdx.x * 256 + tid];
    __syncthreads();
    int base = blockIdx.x * NPB;
    for (int r = 0; r < NPB / 256; ++r) {
        int i = base + r * 256 + tid;
        if (i < N) {
            int b = deg_bin(start, i);
            int gpos = atomicAdd(&cur[b], 1);
            if ((unsigned)gpos < (unsigned)N) perm[gpos] = i;
        }
    }
}

__global__ void pd4_inv(const int* __restrict__ perm, int* __restrict__ iperm, int N) {
    int j = blockIdx.x * 256 + threadIdx.x;
    if (j < N) {
        int node = perm[j];
        if ((unsigned)node < (unsigned)N) iperm[node] = j;
    }
}

// nodepack[j] = {node, start[node], end[node], selfw[node]}
__global__ void p4_pack(const int* __restrict__ perm, const int* __restrict__ start,
                        const float* __restrict__ selfw, int4* __restrict__ nodepack,
                        int N) {
    int j = blockIdx.x * 256 + threadIdx.x;
    if (j < N) {
        int node = perm[j];
        nodepack[j] = make_int4(node, start[node], start[node + 1],
                                __float_as_int(selfw[node]));
    }
}

// S7: edge-parallel per bucket: (row|colL<<17, w) -> (iperm[row], norm).
// Pads EPAD zero entries past E (agg's unguarded pipeline prefetch).
__global__ __launch_bounds__(256)
void s7_norm(const int* __restrict__ bStart, int2* __restrict__ epack,
             const float* __restrict__ dis, const int* __restrict__ iperm, int E) {
    int b = blockIdx.x;
    if (b == 0 && threadIdx.x < EPAD) epack[E + threadIdx.x] = make_int2(0, 0);
    int s = bStart[b], e = bStart[b + 1];
    int cbase = b * CPB;
    for (int p = s + threadIdx.x; p < e; p += 256) {
        int2 d = epack[p];
        int row = d.x & 0x1FFFF;
        int col = cbase + ((d.x >> 17) & (CPB - 1));
        float nm = __fmul_rn(__fmul_rn(dis[row], __int_as_float(d.y)), dis[col]);
        epack[p] = make_int2(iperm[row], __float_as_int(nm));
    }
}

// ---------------------------------------------------------------------------
// gemm0: hw0[j] = x[perm[j]] @ W0 (K=128 -> 16). Sequential-k fmaf.
// R15: stores split into hwLo[N][8] (quads 0,1) / hwHi[N][8] (quads 2,3),
// nt stores (read next kernel from L3; keeps L2 clean).
// ---------------------------------------------------------------------------
__global__ __launch_bounds__(256)
void gemm0(const float* __restrict__ h, const float* __restrict__ W,
           float* __restrict__ hwLo, float* __restrict__ hwHi,
           const int* __restrict__ perm, int N, int K) {
    int g = blockIdx.x * 256 + threadIdx.x;
    int i = g >> 2, jq = g & 3;
    if (i >= N) return;
    int row = perm[i];
    const float4* hv = (const float4*)(h + (long)row * K);
    const float4* Wv = (const float4*)W;
    float4 acc = make_float4(0.f, 0.f, 0.f, 0.f);
    for (int k4 = 0; k4 < K / 4; ++k4) {
        float4 h4 = hv[k4];
        float4 w0 = Wv[(4 * k4 + 0) * 4 + jq];
        acc.x = fmaf(h4.x, w0.x, acc.x); acc.y = fmaf(h4.x, w0.y, acc.y);
        acc.z = fmaf(h4.x, w0.z, acc.z); acc.w = fmaf(h4.x, w0.w, acc.w);
        float4 w1 = Wv[(4 * k4 + 1) * 4 + jq];
        acc.x = fmaf(h4.y, w1.x, acc.x); acc.y = fmaf(h4.y, w1.y, acc.y);
        acc.z = fmaf(h4.y, w1.z, acc.z); acc.w = fmaf(h4.y, w1.w, acc.w);
        float4 w2 = Wv[(4 * k4 + 2) * 4 + jq];
        acc.x = fmaf(h4.z, w2.x, acc.x); acc.y = fmaf(h4.z, w2.y, acc.y);
        acc.z = fmaf(h4.z, w2.z, acc.z); acc.w = fmaf(h4.z, w2.w, acc.w);
        float4 w3 = Wv[(4 * k4 + 3) * 4 + jq];
        acc.x = fmaf(h4.w, w3.x, acc.x); acc.y = fmaf(h4.w, w3.y, acc.y);
        acc.z = fmaf(h4.w, w3.z, acc.z); acc.w = fmaf(h4.w, w3.w, acc.w);
    }
    if (jq < 2) stnt4(&((float4*)hwLo)[(long)i * 2 + jq], acc);
    else        stnt4(&((float4*)hwHi)[(long)i * 2 + (jq - 2)], acc);
}

#define FOLD(dd, gg) { float nm = __int_as_float(dd.y); \
    acc.x = __fadd_rn(acc.x, __fmul_rn(nm, gg.x)); \
    acc.y = __fadd_rn(acc.y, __fmul_rn(nm, gg.y)); \
    acc.z = __fadd_rn(acc.z, __fmul_rn(nm, gg.z)); \
    acc.w = __fadd_rn(acc.w, __fmul_rn(nm, gg.w)); }

// One pipeline step over a 4-edge chunk (roles rotate by NAME, not copies):
// gathers chunk B (epack nt-loaded 2 steps ago, table is L2-resident),
// FOLD chunk A, then nt-load chunk A+12 indices into A's registers.
// Requires in scope: tbl (const float4*, row stride 2 quads), qid, p, epack, acc.
#define STEPH(A0,A1,A2,A3, B0,B1,B2,B3, GA0,GA1,GA2,GA3, GB0,GB1,GB2,GB3) { \
    GB0 = tbl[B0.x * 2 + qid]; GB1 = tbl[B1.x * 2 + qid];                   \
    GB2 = tbl[B2.x * 2 + qid]; GB3 = tbl[B3.x * 2 + qid];                   \
    FOLD(A0, GA0) FOLD(A1, GA1) FOLD(A2, GA2) FOLD(A3, GA3)                 \
    A0 = ldnt2(epack + p + 12); A1 = ldnt2(epack + p + 13);                 \
    A2 = ldnt2(epack + p + 14); A3 = ldnt2(epack + p + 15);                 \
    p += 4; }

// Full 3-bank rotating pipeline over edges [s,e). FOLD order strictly
// ascending edge order (bit-exact). Needs: tbl, qid, epack, s, e, acc.
#define PIPE_LOOP() \
    int2 A0 = ldnt2(epack + s),      A1 = ldnt2(epack + s + 1),             \
         A2 = ldnt2(epack + s + 2),  A3 = ldnt2(epack + s + 3);             \
    int2 B0 = ldnt2(epack + s + 4),  B1 = ldnt2(epack + s + 5),             \
         B2 = ldnt2(epack + s + 6),  B3 = ldnt2(epack + s + 7);             \
    int2 C0 = ldnt2(epack + s + 8),  C1 = ldnt2(epack + s + 9),             \
         C2 = ldnt2(epack + s + 10), C3 = ldnt2(epack + s + 11);            \
    float4 GA0 = tbl[A0.x * 2 + qid], GA1 = tbl[A1.x * 2 + qid],            \
           GA2 = tbl[A2.x * 2 + qid], GA3 = tbl[A3.x * 2 + qid];            \
    float4 GB0, GB1, GB2, GB3, GC0, GC1, GC2, GC3;                          \
    int p = s;                                                              \
    int nfull = (e - s) >> 2;                                               \
    int t = 0;                                                              \
    while (t + 3 <= nfull) {                                                \
        STEPH(A0,A1,A2,A3, B0,B1,B2,B3, GA0,GA1,GA2,GA3, GB0,GB1,GB2,GB3)   \
        STEPH(B0,B1,B2,B3, C0,C1,C2,C3, GB0,GB1,GB2,GB3, GC0,GC1,GC2,GC3)   \
        STEPH(C0,C1,C2,C3, A0,A1,A2,A3, GC0,GC1,GC2,GC3, GA0,GA1,GA2,GA3)   \
        t += 3;                                                             \
    }                                                                       \
    if (t < nfull) { STEPH(A0,A1,A2,A3, B0,B1,B2,B3, GA0,GA1,GA2,GA3, GB0,GB1,GB2,GB3) ++t; } \
    if (t < nfull) { STEPH(B0,B1,B2,B3, C0,C1,C2,C3, GB0,GB1,GB2,GB3, GC0,GC1,GC2,GC3) ++t; } \
    {   int rem = e - p; int m = nfull % 3;                                 \
        if (m == 0) {                                                       \
            if (rem > 0) FOLD(A0, GA0)                                      \
            if (rem > 1) FOLD(A1, GA1)                                      \
            if (rem > 2) FOLD(A2, GA2)                                      \
        } else if (m == 1) {                                                \
            if (rem > 0) FOLD(B0, GB0)                                      \
            if (rem > 1) FOLD(B1, GB1)                                      \
            if (rem > 2) FOLD(B2, GB2)                                      \
        } else {                                                            \
            if (rem > 0) FOLD(C0, GC0)                                      \
            if (rem > 1) FOLD(C1, GC1)                                      \
            if (rem > 2) FOLD(C2, GC2)                                      \
        } }

#define SELF_BIAS_RELU(bq) {                                                \
    float4 sv = tbl[(long)j * 2 + qid];                                     \
    acc.x = __fadd_rn(acc.x, __fmul_rn(sw, sv.x));                          \
    acc.y = __fadd_rn(acc.y, __fmul_rn(sw, sv.y));                          \
    acc.z = __fadd_rn(acc.z, __fmul_rn(sw, sv.z));                          \
    acc.w = __fadd_rn(acc.w, __fmul_rn(sw, sv.w));                          \
    float4 bv = ((const float4*)bias)[bq];                                  \
    acc.x = fmaxf(__fadd_rn(acc.x, bv.x), 0.f);                             \
    acc.y = fmaxf(__fadd_rn(acc.y, bv.y), 0.f);                             \
    acc.z = fmaxf(__fadd_rn(acc.z, bv.z), 0.f);                             \
    acc.w = fmaxf(__fadd_rn(acc.w, bv.w), 0.f); }

// ---------------------------------------------------------------------------
// R15 half-feature passes: gather table is 3.2MB ([N][8] floats) -> fits a
// 4MB per-XCD L2. nt index/stream loads + nt outputs protect table residency.
// 2 threads per node (qid = quad within half). Per-feature aggregation order
// unchanged (stable edge order, self, bias, relu) — bit-exact.
// ---------------------------------------------------------------------------

// Pass A: lo half (feats 0..7): agg + relu -> hL[N][8].
__global__ __launch_bounds__(256)
void aggA(const float* __restrict__ hwLo, const int2* __restrict__ epack,
          const int4* __restrict__ nodepack, const float* __restrict__ bias,
          float* __restrict__ hL, int N) {
    int g = blockIdx.x * 256 + threadIdx.x;
    int j = g >> 1, qid = g & 1;
    if (j >= N) return;
    const float4* tbl = (const float4*)hwLo;
    int4 np = nodepack[j];
    int s = np.y, e = np.z;
    float sw = __int_as_float(np.w);
    float4 acc = make_float4(0.f, 0.f, 0.f, 0.f);
    PIPE_LOOP()
    SELF_BIAS_RELU(qid)
    stnt4(&((float4*)hL)[(long)j * 2 + qid], acc);
}

// Pass B: hi half (feats 8..15): agg + relu, then fused next-layer gemm.
// Full h assembled from hL (lo, linear nt loads) + own/partner acc (shfl).
// Thread qid computes output quads {2*qid, 2*qid+1} (k ascending chain).
#define ACCROW(hcomp, f, kq, o) { float4 wv_ = Wv[(f) * GQ + (kq)];         \
    o.x = fmaf(hcomp, wv_.x, o.x); o.y = fmaf(hcomp, wv_.y, o.y);           \
    o.z = fmaf(hcomp, wv_.z, o.z); o.w = fmaf(hcomp, wv_.w, o.w); }
#define DOTQ(kq, o) {                                                       \
    ACCROW(hq0.x, 0, kq, o)  ACCROW(hq0.y, 1, kq, o)                        \
    ACCROW(hq0.z, 2, kq, o)  ACCROW(hq0.w, 3, kq, o)                        \
    ACCROW(hq1.x, 4, kq, o)  ACCROW(hq1.y, 5, kq, o)                        \
    ACCROW(hq1.z, 6, kq, o)  ACCROW(hq1.w, 7, kq, o)                        \
    ACCROW(hq2.x, 8, kq, o)  ACCROW(hq2.y, 9, kq, o)                        \
    ACCROW(hq2.z, 10, kq, o) ACCROW(hq2.w, 11, kq, o)                       \
    ACCROW(hq3.x, 12, kq, o) ACCROW(hq3.y, 13, kq, o)                       \
    ACCROW(hq3.z, 14, kq, o) ACCROW(hq3.w, 15, kq, o) }

template <int GQ>
__global__ __launch_bounds__(256)
void aggB(const float* __restrict__ hwHi, const float* __restrict__ hL,
          const int2* __restrict__ epack, const int4* __restrict__ nodepack,
          const float* __restrict__ bias, const float* __restrict__ W,
          float* __restrict__ LoOut, float* __restrict__ HiOut, int N) {
    int g = blockIdx.x * 256 + threadIdx.x;
    int j = g >> 1, qid = g & 1;
    if (j >= N) return;
    const float4* tbl = (const float4*)hwHi;
    int4 np = nodepack[j];
    int s = np.y, e = np.z;
    float sw = __int_as_float(np.w);
    float4 acc = make_float4(0.f, 0.f, 0.f, 0.f);
    PIPE_LOOP()
    SELF_BIAS_RELU(2 + qid)

    // assemble h[16]: hq0,hq1 from hL (nt linear), hq2,hq3 from lane pair
    int lane = threadIdx.x & 63;
    int b2 = lane & ~1;
    float4 hq2, hq3;
    hq2.x = __shfl(acc.x, b2, 64);     hq2.y = __shfl(acc.y, b2, 64);
    hq2.z = __shfl(acc.z, b2, 64);     hq2.w = __shfl(acc.w, b2, 64);
    hq3.x = __shfl(acc.x, b2 + 1, 64); hq3.y = __shfl(acc.y, b2 + 1, 64);
    hq3.z = __shfl(acc.z, b2 + 1, 64); hq3.w = __shfl(acc.w, b2 + 1, 64);
    float4 hq0 = ldnt4(&((const float4*)hL)[(long)j * 2 + 0]);
    float4 hq1 = ldnt4(&((const float4*)hL)[(long)j * 2 + 1]);

    const float4* Wv = (const float4*)W;
    int kq0 = 2 * qid, kq1 = 2 * qid + 1;
    float4 o0 = make_float4(0.f, 0.f, 0.f, 0.f);
    float4 o1 = make_float4(0.f, 0.f, 0.f, 0.f);
    DOTQ(kq0, o0)
    if (kq1 < GQ) DOTQ(kq1, o1)

    if (kq0 < 2) stnt4(&((float4*)LoOut)[(long)j * 2 + kq0], o0);
    else         stnt4(&((float4*)HiOut)[(long)j * 2 + (kq0 - 2)], o0);
    if (kq1 < GQ) {
        if (kq1 < 2) stnt4(&((float4*)LoOut)[(long)j * 2 + kq1], o1);
        else         stnt4(&((float4*)HiOut)[(long)j * 2 + (kq1 - 2)], o1);
    }
}

// Final agg (input 12-wide, no gemm): pass A over lo 8 feats -> d_out quads
// 0,1 (original node id); pass B over hi 4 feats (1 thread/node) -> quad 2.
__global__ __launch_bounds__(256)
void agg_lastA(const float* __restrict__ hwLo, const int2* __restrict__ epack,
               const int4* __restrict__ nodepack, const float* __restrict__ bias,
               float* __restrict__ out, int N) {
    int g = blockIdx.x * 256 + threadIdx.x;
    int j = g >> 1, qid = g & 1;
    if (j >= N) return;
    const float4* tbl = (const float4*)hwLo;
    int4 np = nodepack[j];
    int s = np.y, e = np.z;
    float sw = __int_as_float(np.w);
    float4 acc = make_float4(0.f, 0.f, 0.f, 0.f);
    PIPE_LOOP()
    SELF_BIAS_RELU(qid)
    stnt4(&((float4*)out)[(long)np.x * 3 + qid], acc);
}

__global__ __launch_bounds__(256)
void agg_lastB(const float* __restrict__ hwHi, const int2* __restrict__ epack,
               const int4* __restrict__ nodepack, const float* __restrict__ bias,
               float* __restrict__ out, int N) {
    int j = blockIdx.x * 256 + threadIdx.x;
    if (j >= N) return;
    const int qid = 0;
    const float4* tbl = (const float4*)hwHi;
    int4 np = nodepack[j];
    int s = np.y, e = np.z;
    float sw = __int_as_float(np.w);
    float4 acc = make_float4(0.f, 0.f, 0.f, 0.f);
    PIPE_LOOP()
    SELF_BIAS_RELU(2)
    stnt4(&((float4*)out)[(long)np.x * 3 + 2], acc);
}

// ---------------------------------------------------------------------------

extern "C" void kernel_launch(void* const* d_in, const int* in_sizes, int n_in,
                              void* d_out, int out_size, void* d_ws, size_t ws_size,
                              hipStream_t stream) {
    const float* x      = (const float*)d_in[0];
    const int*   ei     = (const int*)d_in[1];
    const float* ew     = (const float*)d_in[2];
    const float* W0     = (const float*)d_in[3];
    const float* b0     = (const float*)d_in[4];
    const float* Wmid   = (const float*)d_in[5];
    const float* bmid   = (const float*)d_in[6];
    const float* Wlast  = (const float*)d_in[7];
    const float* blast  = (const float*)d_in[8];

    const int N = in_sizes[0] / DIN;              // 100000
    const int E = in_sizes[2];                    // 3200000
    const int* row32 = ei;
    const int* col32 = ei + E;
    const int nblk = (E + EPB - 1) / EPB;         // 1563
    const int NB   = (N + CPB - 1) / CPB;         // 782
    const int nbk  = (N + NPB - 1) / NPB;         // 98

    char* w = (char*)d_ws;
    size_t off = 0;
    auto alloc = [&](size_t bytes) -> void* {
        void* p = w + off;
        off = (off + bytes + 255) & ~(size_t)255;
        return p;
    };
    int*  T      = (int*)alloc((size_t)NB * 4);
    int*  bStart = (int*)alloc((size_t)(NB + 1) * 4);
    int*  H      = (int*)alloc((size_t)nblk * NB * 4);
    int*  O      = (int*)alloc((size_t)nblk * NB * 4);
    int*  start  = (int*)alloc((size_t)(N + 1) * 4);
    float* dis   = (float*)alloc((size_t)N * 4);
    float* selfw = (float*)alloc((size_t)N * 4);
    int*  HD     = (int*)alloc((size_t)nbk * 256 * 4);
    int*  OD     = (int*)alloc((size_t)nbk * 256 * 4);
    int*  binStart = (int*)alloc(257 * 4);
    int*  perm   = (int*)alloc((size_t)N * 4);
    int*  iperm  = (int*)alloc((size_t)N * 4);
    int4* nodepack = (int4*)alloc((size_t)N * 16);
    int2* bins   = (int2*)alloc(((size_t)E + EPAD) * 8); // pad for agg prefetch
    float* hLoA  = (float*)alloc((size_t)N * 8 * 4);
    float* hHiA  = (float*)alloc((size_t)N * 8 * 4);
    float* hLoB  = (float*)alloc((size_t)N * 8 * 4);
    float* hHiB  = (float*)alloc((size_t)N * 8 * 4);
    float* hL    = (float*)alloc((size_t)N * 8 * 4);
    (void)ws_size;

    hipMemsetAsync(T, 0, (size_t)NB * 4, stream);

    int gridN1 = (N + 255) / 256;
    int gridN2 = (N * 2 + 255) / 256;
    int gridN4 = (N * 4 + 255) / 256;

    s1_hist<<<nblk, 256, 0, stream>>>(col32, H, T, E, N, NB);
    s2b_scan<<<1, 1024, 0, stream>>>(T, bStart, NB);
    s2c_scan<<<(NB * 64 + 255) / 256, 256, 0, stream>>>(H, bStart, O, NB, nblk);
    s3_bin<<<nblk, 256, 0, stream>>>(row32, col32, ew, O, bins, E, N, NB);
    s4_sort<<<NB, 256, 0, stream>>>(bStart, bins, start, dis, selfw, E, N);
    pd1_hist<<<nbk, 256, 0, stream>>>(start, HD, N);
    pd2a_scan<<<1, 256, 0, stream>>>(HD, binStart, nbk);
    pd2b_off<<<64, 256, 0, stream>>>(HD, binStart, OD, nbk);
    pd3_fill<<<nbk, 256, 0, stream>>>(start, OD, perm, N);
    pd4_inv<<<gridN1, 256, 0, stream>>>(perm, iperm, N);
    p4_pack<<<gridN1, 256, 0, stream>>>(perm, start, selfw, nodepack, N);
    s7_norm<<<NB, 256, 0, stream>>>(bStart, bins, dis, iperm, E);
    int2* epack = bins;

    gemm0<<<gridN4, 256, 0, stream>>>(x, W0, hLoA, hHiA, perm, N, DIN);

    // 12 layers, each = pass A (lo agg -> hL) + pass B (hi agg + fused gemm)
    float* Lo[2] = {hLoA, hLoB};
    float* Hi[2] = {hHiA, hHiB};
    for (int i = 0; i < 12; ++i) {
        const float* bias = (i == 0) ? b0 : bmid + (size_t)(i - 1) * HID;
        aggA<<<gridN2, 256, 0, stream>>>(Lo[i & 1], epack, nodepack, bias, hL, N);
        if (i < 11) {
            const float* Wn = Wmid + (size_t)i * HID * HID;
            aggB<4><<<gridN2, 256, 0, stream>>>(Hi[i & 1], hL, epack, nodepack,
                                                bias, Wn, Lo[(i + 1) & 1],
                                                Hi[(i + 1) & 1], N);
        } else {
            aggB<3><<<gridN2, 256, 0, stream>>>(Hi[1], hL, epack, nodepack,
                                                bias, Wlast, Lo[0], Hi[0], N);
        }
    }
    // final agg over 12-wide (lo 8 + hi 4) -> d_out in original node order
    agg_lastA<<<gridN2, 256, 0, stream>>>(Lo[0], epack, nodepack, blast,
                                          (float*)d_out, N);
    agg_lastB<<<gridN1, 256, 0, stream>>>(Hi[0], epack, nodepack, blast,
                                          (float*)d_out, N);
}

// Round 7
// 945.743 us; speedup vs baseline: 1.8446x; 1.8446x over previous
//
#include <hip/hip_runtime.h>
#include <math.h>

#define DIN 128
#define HID 16
#define DOUT 12
#define NMID 11

#define CPB 128        // cols per bucket (col >> 7)
#define NBMAX 800      // max coarse buckets (runtime 782)
#define EPB 4096       // edges per binning block (R10 best-total prep)
#define EPW (EPB / 4)  // edges per wave (contiguous chunk)
#define CAP 5120       // max edges per bucket in s4 LDS
#define NPB 1024       // nodes per perm-build block
#define EPAD 16        // epack tail padding

#define SLICE 1264     // staged epack entries per wave (16 nodes, avg deg 32)
#define SEGSZ (4 * SLICE + 8)   // + read-overhang pad; 39.6KB -> 4 blocks/CU

typedef unsigned long long ull;

// non-temporal 8B load of an int2 (evict-first: keeps hw table L2-resident)
__device__ __forceinline__ int2 ldnt2(const int2* p) {
    ull v = __builtin_nontemporal_load((const ull*)p);
    return make_int2((int)(unsigned)(v & 0xffffffffull), (int)(unsigned)(v >> 32));
}

// exclusive scan in place over arr[0..L), 256 threads, L <= 1024
__device__ __forceinline__ void scan4(int* arr, int L, int tid, int* wtot) {
    int lane = tid & 63, wid = tid >> 6;
    int v[4]; int s = 0;
#pragma unroll
    for (int j = 0; j < 4; ++j) {
        int idx = tid * 4 + j;
        int t = (idx < L) ? arr[idx] : 0;
        v[j] = s; s += t;
    }
    int x = s;
    for (int off = 1; off < 64; off <<= 1) {
        int y = __shfl_up(x, off, 64);
        if (lane >= off) x += y;
    }
    if (lane == 63) wtot[wid] = x;
    __syncthreads();
    if (tid == 0) { int c = 0; for (int i = 0; i < 4; ++i) { int t = wtot[i]; wtot[i] = c; c += t; } }
    __syncthreads();
    int b0 = wtot[wid] + (x - s);
#pragma unroll
    for (int j = 0; j < 4; ++j) {
        int idx = tid * 4 + j;
        if (idx < L) arr[idx] = b0 + v[j];
    }
    __syncthreads();
}

// S1: per-block coarse histogram + global bucket totals.
__global__ __launch_bounds__(256)
void s1_hist(const int* __restrict__ col, int* __restrict__ H, int* __restrict__ T,
             int E, int N, int NB) {
    __shared__ int hist[NBMAX];
    int tid = threadIdx.x;
    for (int i = tid; i < NB; i += 256) hist[i] = 0;
    __syncthreads();
    long base = (long)blockIdx.x * EPB;
    for (int r = 0; r < EPB / 256; ++r) {
        long e = base + r * 256 + tid;
        if (e < E) {
            int c = col[e];
            if ((unsigned)c < (unsigned)N) atomicAdd(&hist[c >> 7], 1);
        }
    }
    __syncthreads();
    for (int i = tid; i < NB; i += 256) {
        int h = hist[i];
        H[(long)blockIdx.x * NB + i] = h;
        if (h) atomicAdd(&T[i], h);
    }
}

// S2b: exclusive scan of bucket totals -> bStart[0..NB], single block.
__global__ __launch_bounds__(1024)
void s2b_scan(const int* __restrict__ T, int* __restrict__ bStart, int NB) {
    __shared__ int wtot[16];
    int tid = threadIdx.x, lane = tid & 63, wid = tid >> 6;
    int v = (tid < NB) ? T[tid] : 0;
    int x = v;
    for (int off = 1; off < 64; off <<= 1) {
        int y = __shfl_up(x, off, 64);
        if (lane >= off) x += y;
    }
    if (lane == 63) wtot[wid] = x;
    __syncthreads();
    if (tid == 0) { int c = 0; for (int i = 0; i < 16; ++i) { int t = wtot[i]; wtot[i] = c; c += t; } }
    __syncthreads();
    int excl = wtot[wid] + x - v;
    if (tid < NB) {
        bStart[tid] = excl;
        if (tid == NB - 1) bStart[NB] = excl + v;
    }
}

// S2c: per-(block,bucket) reservation offsets. One wave per bucket.
__global__ __launch_bounds__(256)
void s2c_scan(const int* __restrict__ H, const int* __restrict__ bStart,
              int* __restrict__ O, int NB, int nblk) {
    int wv = (blockIdx.x * 256 + threadIdx.x) >> 6;
    int lane = threadIdx.x & 63;
    if (wv >= NB) return;
    int run = bStart[wv];
    for (int k0 = 0; k0 < nblk; k0 += 64) {
        int k = k0 + lane;
        int h = (k < nblk) ? H[(long)k * NB + wv] : 0;
        int x = h;
        for (int off = 1; off < 64; off <<= 1) {
            int y = __shfl_up(x, off, 64);
            if (lane >= off) x += y;
        }
        if (k < nblk) O[(long)k * NB + wv] = run + (x - h);
        run += __shfl(x, 63, 64);
    }
}

// S3 (R10 form): stable bin by coarse bucket. Wave-private cursors + LDS
// staging with coalesced flush. Stable & deterministic.
__global__ __launch_bounds__(256)
void s3_bin(const int* __restrict__ row, const int* __restrict__ col,
            const float* __restrict__ ew, const int* __restrict__ O,
            int2* __restrict__ bins, int E, int N, int NB) {
    __shared__ int wh[4][NBMAX];       // per-wave hist -> per-wave cursor
    __shared__ int cnt[NBMAX];         // block totals -> scan -> dlt (reused)
    __shared__ int2 ldata[EPB];
    __shared__ unsigned short bdst[EPB];
    __shared__ int wtot[4];
    int tid = threadIdx.x;
    int lane = tid & 63, wid = tid >> 6;
    long base  = (long)blockIdx.x * EPB;
    long wbase = base + (long)wid * EPW;
    for (int i = tid; i < NB; i += 256) {
        wh[0][i] = 0; wh[1][i] = 0; wh[2][i] = 0; wh[3][i] = 0;
    }
    __syncthreads();
    for (int r = 0; r < EPW / 64; ++r) {
        long e = wbase + r * 64 + lane;
        if (e < E) {
            int c = col[e];
            if ((unsigned)c < (unsigned)N) atomicAdd(&wh[wid][c >> 7], 1);
        }
    }
    __syncthreads();
    for (int i = tid; i < NB; i += 256)
        cnt[i] = wh[0][i] + wh[1][i] + wh[2][i] + wh[3][i];
    __syncthreads();
    scan4(cnt, NB, tid, wtot);         // cnt = block-local bucket starts
    for (int i = tid; i < NB; i += 256) {
        int b0 = cnt[i];
        int h0 = wh[0][i], h1 = wh[1][i], h2 = wh[2][i];
        wh[0][i] = b0;
        wh[1][i] = b0 + h0;
        wh[2][i] = b0 + h0 + h1;
        wh[3][i] = b0 + h0 + h1 + h2;
        cnt[i] = O[(long)blockIdx.x * NB + i] - b0;   // dlt (cnt reused)
    }
    __syncthreads();
    ull ltm = (lane == 0) ? 0ULL : ((~0ULL) >> (64 - lane));
    for (int r = 0; r < EPW / 64; ++r) {
        long e = wbase + r * 64 + lane;
        bool valid = (e < E);
        int c = 0;
        if (valid) { c = col[e]; valid = ((unsigned)c < (unsigned)N); }
        int b = valid ? (c >> 7) : 0;
        int rw = 0; float wv = 0.f;
        if (valid) { rw = row[e]; wv = ew[e]; }
        ull peers = __ballot(valid);
        for (int bit = 0; bit < 10; ++bit) {
            ull s = __ballot(valid && ((b >> bit) & 1));
            peers &= ((b >> bit) & 1) ? s : ~s;
        }
        int rank = __popcll(peers & ltm);
        int cng  = __popcll(peers);
        int ldr  = __ffsll(peers) - 1;
        if (ldr < 0) ldr = 0;
        int lb = 0;
        if (valid && rank == 0) lb = atomicAdd(&wh[wid][b], cng);
        int lbase = __shfl(lb, ldr, 64);
        if (valid) {
            int lpos = lbase + rank;
            if ((unsigned)lpos < (unsigned)EPB) {
                ldata[lpos] = make_int2(rw | ((c & (CPB - 1)) << 17), __float_as_int(wv));
                bdst[lpos]  = (unsigned short)b;
            }
        }
    }
    __syncthreads();
    int lenBlock = (int)((E - base < (long)EPB) ? (E - base) : (long)EPB);
    for (int p = tid; p < lenBlock; p += 256) {
        int g = p + cnt[bdst[p]];
        if ((unsigned)g < (unsigned)E) bins[g] = ldata[p];
    }
}

// S4: per-bucket stable counting sort by local col, wave-private cursors.
__global__ __launch_bounds__(256)
void s4_sort(const int* __restrict__ bStart, int2* bins,
             int* __restrict__ start, float* __restrict__ dis,
             float* __restrict__ selfw, int E, int N) {
    __shared__ int2 ldata[CAP];
    __shared__ int wh[4][CPB];
    __shared__ int colStart[CPB + 1];
    __shared__ int wtot[4];
    int b = blockIdx.x;
    int tid = threadIdx.x;
    int lane = tid & 63, wid = tid >> 6;
    int segs = bStart[b], sege = bStart[b + 1];
    int len = sege - segs;
    if (len > CAP) len = CAP;
    if (tid < CPB) { wh[0][tid] = 0; wh[1][tid] = 0; wh[2][tid] = 0; wh[3][tid] = 0; }
    __syncthreads();
    int rounds = (len + 255) / 256;
    int chunk = rounds * 64;
    int ws = wid * chunk; if (ws > len) ws = len;
    int we = ws + chunk;  if (we > len) we = len;
    for (int p = ws + lane; p < we; p += 64)
        atomicAdd(&wh[wid][(bins[segs + p].x >> 17) & (CPB - 1)], 1);
    __syncthreads();
    if (tid < CPB) colStart[tid] = wh[0][tid] + wh[1][tid] + wh[2][tid] + wh[3][tid];
    __syncthreads();
    scan4(colStart, CPB, tid, wtot);
    if (tid == 0) colStart[CPB] = len;
    if (tid < CPB) {
        int b0 = colStart[tid];
        int h0 = wh[0][tid], h1 = wh[1][tid], h2 = wh[2][tid];
        wh[0][tid] = b0;
        wh[1][tid] = b0 + h0;
        wh[2][tid] = b0 + h0 + h1;
        wh[3][tid] = b0 + h0 + h1 + h2;
        int cg = b * CPB + tid;
        if (cg < N) start[cg] = segs + b0;
    }
    if (b == (int)gridDim.x - 1 && tid == 0) start[N] = sege;
    __syncthreads();
    ull ltm = (lane == 0) ? 0ULL : ((~0ULL) >> (64 - lane));
    for (int p0 = ws; p0 < we; p0 += 64) {
        int p = p0 + lane;
        bool valid = (p < we);
        int2 d = valid ? bins[segs + p] : make_int2(0, 0);
        int c = valid ? ((d.x >> 17) & (CPB - 1)) : 0;
        ull peers = __ballot(valid);
        for (int bit = 0; bit < 7; ++bit) {
            ull s = __ballot(valid && ((c >> bit) & 1));
            peers &= ((c >> bit) & 1) ? s : ~s;
        }
        int rank = __popcll(peers & ltm);
        int cng  = __popcll(peers);
        int ldr  = __ffsll(peers) - 1;
        if (ldr < 0) ldr = 0;
        int lb = 0;
        if (valid && rank == 0) lb = atomicAdd(&wh[wid][c], cng);
        int lbase = __shfl(lb, ldr, 64);
        if (valid) {
            int lpos = lbase + rank;
            if ((unsigned)lpos < (unsigned)CAP) ldata[lpos] = d;
        }
    }
    __syncthreads();
    for (int p = tid; p < len; p += 256)
        bins[segs + p] = ldata[p];
    if (tid < CPB) {
        int cg = b * CPB + tid;
        if (cg < N) {
            int s0 = colStart[tid], e0 = colStart[tid + 1];
            float dsum = 0.f;
            for (int q = s0; q < e0; ++q)
                dsum = __fadd_rn(dsum, __int_as_float(ldata[q].y));
            dsum = __fadd_rn(dsum, 1.0f);
            dis[cg] = 1.0f / __fsqrt_rn(dsum);
            selfw[cg] = 1.0f / dsum;
        }
    }
}

// ---------------------------------------------------------------------------
// Degree-sorted node permutation (scan-built).
// ---------------------------------------------------------------------------

__device__ __forceinline__ int deg_bin(const int* start, int i) {
    int d = start[i + 1] - start[i];
    return 255 - (d > 255 ? 255 : d);
}

__global__ __launch_bounds__(256)
void pd1_hist(const int* __restrict__ start, int* __restrict__ HD, int N) {
    __shared__ int hist[256];
    int tid = threadIdx.x;
    hist[tid] = 0;
    __syncthreads();
    int base = blockIdx.x * NPB;
    for (int r = 0; r < NPB / 256; ++r) {
        int i = base + r * 256 + tid;
        if (i < N) atomicAdd(&hist[deg_bin(start, i)], 1);
    }
    __syncthreads();
    HD[blockIdx.x * 256 + tid] = hist[tid];
}

__global__ __launch_bounds__(256)
void pd2a_scan(const int* __restrict__ HD, int* __restrict__ binStart, int nbk) {
    __shared__ int arr[256];
    __shared__ int wtot[4];
    int tid = threadIdx.x;
    int tot = 0;
    for (int k = 0; k < nbk; ++k) tot += HD[k * 256 + tid];
    arr[tid] = tot;
    __syncthreads();
    scan4(arr, 256, tid, wtot);
    binStart[tid] = arr[tid];
}

__global__ __launch_bounds__(256)
void pd2b_off(const int* __restrict__ HD, const int* __restrict__ binStart,
              int* __restrict__ OD, int nbk) {
    int wv = (blockIdx.x * 256 + threadIdx.x) >> 6;
    int lane = threadIdx.x & 63;
    if (wv >= 256) return;
    int run = binStart[wv];
    for (int k0 = 0; k0 < nbk; k0 += 64) {
        int k = k0 + lane;
        int h = (k < nbk) ? HD[k * 256 + wv] : 0;
        int x = h;
        for (int off = 1; off < 64; off <<= 1) {
            int y = __shfl_up(x, off, 64);
            if (lane >= off) x += y;
        }
        if (k < nbk) OD[k * 256 + wv] = run + (x - h);
        run += __shfl(x, 63, 64);
    }
}

// pd3: permutation need not be stable (any valid permutation leaves all
// arithmetic orders unchanged). Plain per-lane atomic fill.
__global__ __launch_bounds__(256)
void pd3_fill(const int* __restrict__ start, const int* __restrict__ OD,
              int* __restrict__ perm, int N) {
    __shared__ int cur[256];
    int tid = threadIdx.x;
    cur[tid] = OD[blockIdx.x * 256 + tid];
    __syncthreads();
    int base = blockIdx.x * NPB;
    for (int r = 0; r < NPB / 256; ++r) {
        int i = base + r * 256 + tid;
        if (i < N) {
            int b = deg_bin(start, i);
            int gpos = atomicAdd(&cur[b], 1);
            if ((unsigned)gpos < (unsigned)N) perm[gpos] = i;
        }
    }
}

__global__ void pd4_inv(const int* __restrict__ perm, int* __restrict__ iperm, int N) {
    int j = blockIdx.x * 256 + threadIdx.x;
    if (j < N) {
        int node = perm[j];
        if ((unsigned)node < (unsigned)N) iperm[node] = j;
    }
}

// nodepack[j] = {node, start[node], end[node], selfw[node]}
__global__ void p4_pack(const int* __restrict__ perm, const int* __restrict__ start,
                        const float* __restrict__ selfw, int4* __restrict__ nodepack,
                        int N) {
    int j = blockIdx.x * 256 + threadIdx.x;
    if (j < N) {
        int node = perm[j];
        nodepack[j] = make_int4(node, start[node], start[node + 1],
                                __float_as_int(selfw[node]));
    }
}

// S7: edge-parallel per bucket: (row|colL<<17, w) -> (iperm[row], norm).
__global__ __launch_bounds__(256)
void s7_norm(const int* __restrict__ bStart, int2* __restrict__ epack,
             const float* __restrict__ dis, const int* __restrict__ iperm, int E) {
    int b = blockIdx.x;
    if (b == 0 && threadIdx.x < EPAD) epack[E + threadIdx.x] = make_int2(0, 0);
    int s = bStart[b], e = bStart[b + 1];
    int cbase = b * CPB;
    for (int p = s + threadIdx.x; p < e; p += 256) {
        int2 d = epack[p];
        int row = d.x & 0x1FFFF;
        int col = cbase + ((d.x >> 17) & (CPB - 1));
        float nm = __fmul_rn(__fmul_rn(dis[row], __int_as_float(d.y)), dis[col]);
        epack[p] = make_int2(iperm[row], __float_as_int(nm));
    }
}

// ---------------------------------------------------------------------------
// gemm0: hw0[j] = x[perm[j]] @ W0 (K=128 -> 16). Sequential-k fmaf.
// ---------------------------------------------------------------------------
__global__ __launch_bounds__(256)
void gemm0(const float* __restrict__ h, const float* __restrict__ W,
           float* __restrict__ hw, const int* __restrict__ perm, int N, int K) {
    int g = blockIdx.x * 256 + threadIdx.x;
    int i = g >> 2, jq = g & 3;
    if (i >= N) return;
    int row = perm[i];
    const float4* hv = (const float4*)(h + (long)row * K);
    const float4* Wv = (const float4*)W;
    float4 acc = make_float4(0.f, 0.f, 0.f, 0.f);
    for (int k4 = 0; k4 < K / 4; ++k4) {
        float4 h4 = hv[k4];
        float4 w0 = Wv[(4 * k4 + 0) * 4 + jq];
        acc.x = fmaf(h4.x, w0.x, acc.x); acc.y = fmaf(h4.x, w0.y, acc.y);
        acc.z = fmaf(h4.x, w0.z, acc.z); acc.w = fmaf(h4.x, w0.w, acc.w);
        float4 w1 = Wv[(4 * k4 + 1) * 4 + jq];
        acc.x = fmaf(h4.y, w1.x, acc.x); acc.y = fmaf(h4.y, w1.y, acc.y);
        acc.z = fmaf(h4.y, w1.z, acc.z); acc.w = fmaf(h4.y, w1.w, acc.w);
        float4 w2 = Wv[(4 * k4 + 2) * 4 + jq];
        acc.x = fmaf(h4.z, w2.x, acc.x); acc.y = fmaf(h4.z, w2.y, acc.y);
        acc.z = fmaf(h4.z, w2.z, acc.z); acc.w = fmaf(h4.z, w2.w, acc.w);
        float4 w3 = Wv[(4 * k4 + 3) * 4 + jq];
        acc.x = fmaf(h4.w, w3.x, acc.x); acc.y = fmaf(h4.w, w3.y, acc.y);
        acc.z = fmaf(h4.w, w3.z, acc.z); acc.w = fmaf(h4.w, w3.w, acc.w);
    }
    ((float4*)hw)[(long)i * 4 + jq] = acc;
}

#define FOLD(dd, gg) { float nm = __int_as_float(dd.y); \
    acc.x = __fadd_rn(acc.x, __fmul_rn(nm, gg.x)); \
    acc.y = __fadd_rn(acc.y, __fmul_rn(nm, gg.y)); \
    acc.z = __fadd_rn(acc.z, __fmul_rn(nm, gg.z)); \
    acc.w = __fadd_rn(acc.w, __fmul_rn(nm, gg.w)); }

// clamp garbage LDS indices (identity on real data: idx = iperm[..] in [0,N))
#define IX(dd) ((int)min((unsigned)(dd).x, (unsigned)(N - 1)))

// Wave-cooperative LDS staging of the 16 node-segments of this wave:
// nt burst loads (don't install epack stream in L2; index loads leave the
// outstanding-request budget to the table gathers). Declares: seg usage,
// startoff, cnt (per-node staged count). Order & values preserved verbatim.
#define STAGE_SEG()                                                          \
    int len = e - s;                                                         \
    int ni = lane >> 2;                                                      \
    int pre = 0;                                                             \
    for (int i = 0; i < 16; ++i) {                                           \
        int li = __shfl(len, i * 4, 64);                                     \
        if (i < ni) pre += li;                                               \
    }                                                                        \
    int startoff = min(pre, SLICE);                                          \
    int cnt = min(len, SLICE - startoff);                                    \
    for (int i = 0; i < 16; ++i) {                                           \
        int si = __shfl(s, i * 4, 64);                                       \
        int oi = __shfl(startoff, i * 4, 64);                                \
        int ci = __shfl(cnt, i * 4, 64);                                     \
        int bse = wid * SLICE + oi;                                          \
        for (int p = lane; p < ci; p += 64)                                  \
            seg[bse + p] = ldnt2(epack + si + p);                            \
    }

// ---------------------------------------------------------------------------
// agg_fused (R16): LDS-staged indices + R12's 4-deep gather pipeline +
// fused next-layer gemm epilogue. FOLD order: staged [s,s+cnt) ascending,
// then overflow [s+cnt,e) ascending == R12's exact order (bit-identical).
// GQ = output width / 4 (4 for 16-wide Wmid, 3 for 12-wide Wlast).
// ---------------------------------------------------------------------------
template <int GQ>
__global__ __launch_bounds__(256)
void agg_fused(const float* __restrict__ hw, const int2* __restrict__ epack,
               const int4* __restrict__ nodepack, const float* __restrict__ bias,
               const float* __restrict__ W, float* __restrict__ hwout, int N) {
    __shared__ int2 seg[SEGSZ];
    int tid = threadIdx.x;
    int lane = tid & 63, wid = tid >> 6, fq = lane & 3;
    int g = blockIdx.x * 256 + tid;
    int j = g >> 2;
    bool on = (j < N);
    int4 np = on ? nodepack[j] : make_int4(0, 0, 0, 0);
    int s = np.y, e = np.z;
    float sw = __int_as_float(np.w);

    STAGE_SEG()
    if (!on) return;

    const float4* hwv = (const float4*)hw;
    float4 acc = make_float4(0.f, 0.f, 0.f, 0.f);

    int lo = wid * SLICE + startoff;
    int2 d0 = seg[lo],     d1 = seg[lo + 1],
         d2 = seg[lo + 2], d3 = seg[lo + 3];
    float4 g0 = hwv[IX(d0) * 4 + fq], g1 = hwv[IX(d1) * 4 + fq],
           g2 = hwv[IX(d2) * 4 + fq], g3 = hwv[IX(d3) * 4 + fq];
    int p = 0;
    int nfull = cnt >> 2;
    for (int c = 0; c < nfull; ++c) {
        int pn = p + 4;
        int2 e0 = seg[lo + pn],     e1 = seg[lo + pn + 1],
             e2 = seg[lo + pn + 2], e3 = seg[lo + pn + 3];
        float4 h0 = hwv[IX(e0) * 4 + fq], h1 = hwv[IX(e1) * 4 + fq],
               h2 = hwv[IX(e2) * 4 + fq], h3 = hwv[IX(e3) * 4 + fq];
        FOLD(d0, g0) FOLD(d1, g1) FOLD(d2, g2) FOLD(d3, g3)
        d0 = e0; d1 = e1; d2 = e2; d3 = e3;
        g0 = h0; g1 = h1; g2 = h2; g3 = h3;
        p = pn;
    }
    int rem = cnt - p;
    if (rem > 0) FOLD(d0, g0)
    if (rem > 1) FOLD(d1, g1)
    if (rem > 2) FOLD(d2, g2)
    // overflow (staged slice full — rare): direct cached loads, in order
    for (int p2 = s + cnt; p2 < e; ++p2) {
        int2 dd = epack[p2];
        float4 gg = hwv[IX(dd) * 4 + fq];
        FOLD(dd, gg)
    }

    float4 sv = hwv[(long)j * 4 + fq];   // self row: linear in perm space
    acc.x = __fadd_rn(acc.x, __fmul_rn(sw, sv.x));
    acc.y = __fadd_rn(acc.y, __fmul_rn(sw, sv.y));
    acc.z = __fadd_rn(acc.z, __fmul_rn(sw, sv.z));
    acc.w = __fadd_rn(acc.w, __fmul_rn(sw, sv.w));
    float4 bv = ((const float4*)bias)[fq];
    acc.x = fmaxf(__fadd_rn(acc.x, bv.x), 0.f);
    acc.y = fmaxf(__fadd_rn(acc.y, bv.y), 0.f);
    acc.z = fmaxf(__fadd_rn(acc.z, bv.z), 0.f);
    acc.w = fmaxf(__fadd_rn(acc.w, bv.w), 0.f);

    // fused gemm: out_j = sum_k h[k]*W[k][j], k ascending (bit-exact order)
    const float4* Wv = (const float4*)W;
    int lbase = lane & ~3;
    float4 out = make_float4(0.f, 0.f, 0.f, 0.f);
#pragma unroll
    for (int q = 0; q < 4; ++q) {
        int src = lbase + q;
        float4 hh;
        hh.x = __shfl(acc.x, src, 64);
        hh.y = __shfl(acc.y, src, 64);
        hh.z = __shfl(acc.z, src, 64);
        hh.w = __shfl(acc.w, src, 64);
        if (fq < GQ) {
            float4 w0 = Wv[(4 * q + 0) * GQ + fq];
            out.x = fmaf(hh.x, w0.x, out.x); out.y = fmaf(hh.x, w0.y, out.y);
            out.z = fmaf(hh.x, w0.z, out.z); out.w = fmaf(hh.x, w0.w, out.w);
            float4 w1 = Wv[(4 * q + 1) * GQ + fq];
            out.x = fmaf(hh.y, w1.x, out.x); out.y = fmaf(hh.y, w1.y, out.y);
            out.z = fmaf(hh.y, w1.z, out.z); out.w = fmaf(hh.y, w1.w, out.w);
            float4 w2 = Wv[(4 * q + 2) * GQ + fq];
            out.x = fmaf(hh.z, w2.x, out.x); out.y = fmaf(hh.z, w2.y, out.y);
            out.z = fmaf(hh.z, w2.z, out.z); out.w = fmaf(hh.z, w2.w, out.w);
            float4 w3 = Wv[(4 * q + 3) * GQ + fq];
            out.x = fmaf(hh.w, w3.x, out.x); out.y = fmaf(hh.w, w3.y, out.y);
            out.z = fmaf(hh.w, w3.z, out.z); out.w = fmaf(hh.w, w3.w, out.w);
        }
    }
    if (fq < GQ) ((float4*)hwout)[(long)j * GQ + fq] = out;
}

// agg_last (R16): F=12 input (stride 3), LDS-staged, no gemm; scatters to
// d_out by original node id. fq==3 lanes help staging then retire.
__global__ __launch_bounds__(256)
void agg_last(const float* __restrict__ hw, const int2* __restrict__ epack,
              const int4* __restrict__ nodepack, const float* __restrict__ bias,
              float* __restrict__ out, int N) {
    __shared__ int2 seg[SEGSZ];
    int tid = threadIdx.x;
    int lane = tid & 63, wid = tid >> 6, fq = lane & 3;
    int g = blockIdx.x * 256 + tid;
    int j = g >> 2;
    bool on = (j < N);
    int4 np = on ? nodepack[j] : make_int4(0, 0, 0, 0);
    int s = np.y, e = np.z;
    float sw = __int_as_float(np.w);

    STAGE_SEG()
    if (!on || fq >= 3) return;

    const float4* hwv = (const float4*)hw;
    float4 acc = make_float4(0.f, 0.f, 0.f, 0.f);

    int lo = wid * SLICE + startoff;
    int2 d0 = seg[lo],     d1 = seg[lo + 1],
         d2 = seg[lo + 2], d3 = seg[lo + 3];
    float4 g0 = hwv[IX(d0) * 3 + fq], g1 = hwv[IX(d1) * 3 + fq],
           g2 = hwv[IX(d2) * 3 + fq], g3 = hwv[IX(d3) * 3 + fq];
    int p = 0;
    int nfull = cnt >> 2;
    for (int c = 0; c < nfull; ++c) {
        int pn = p + 4;
        int2 e0 = seg[lo + pn],     e1 = seg[lo + pn + 1],
             e2 = seg[lo + pn + 2], e3 = seg[lo + pn + 3];
        float4 h0 = hwv[IX(e0) * 3 + fq], h1 = hwv[IX(e1) * 3 + fq],
               h2 = hwv[IX(e2) * 3 + fq], h3 = hwv[IX(e3) * 3 + fq];
        FOLD(d0, g0) FOLD(d1, g1) FOLD(d2, g2) FOLD(d3, g3)
        d0 = e0; d1 = e1; d2 = e2; d3 = e3;
        g0 = h0; g1 = h1; g2 = h2; g3 = h3;
        p = pn;
    }
    int rem = cnt - p;
    if (rem > 0) FOLD(d0, g0)
    if (rem > 1) FOLD(d1, g1)
    if (rem > 2) FOLD(d2, g2)
    for (int p2 = s + cnt; p2 < e; ++p2) {
        int2 dd = epack[p2];
        float4 gg = hwv[IX(dd) * 3 + fq];
        FOLD(dd, gg)
    }

    float4 sv = hwv[(long)j * 3 + fq];
    acc.x = __fadd_rn(acc.x, __fmul_rn(sw, sv.x));
    acc.y = __fadd_rn(acc.y, __fmul_rn(sw, sv.y));
    acc.z = __fadd_rn(acc.z, __fmul_rn(sw, sv.z));
    acc.w = __fadd_rn(acc.w, __fmul_rn(sw, sv.w));
    float4 bv = ((const float4*)bias)[fq];
    acc.x = fmaxf(__fadd_rn(acc.x, bv.x), 0.f);
    acc.y = fmaxf(__fadd_rn(acc.y, bv.y), 0.f);
    acc.z = fmaxf(__fadd_rn(acc.z, bv.z), 0.f);
    acc.w = fmaxf(__fadd_rn(acc.w, bv.w), 0.f);
    ((float4*)out)[(long)np.x * 3 + fq] = acc;   // scatter to original id
}

// ---------------------------------------------------------------------------

extern "C" void kernel_launch(void* const* d_in, const int* in_sizes, int n_in,
                              void* d_out, int out_size, void* d_ws, size_t ws_size,
                              hipStream_t stream) {
    const float* x      = (const float*)d_in[0];
    const int*   ei     = (const int*)d_in[1];
    const float* ew     = (const float*)d_in[2];
    const float* W0     = (const float*)d_in[3];
    const float* b0     = (const float*)d_in[4];
    const float* Wmid   = (const float*)d_in[5];
    const float* bmid   = (const float*)d_in[6];
    const float* Wlast  = (const float*)d_in[7];
    const float* blast  = (const float*)d_in[8];

    const int N = in_sizes[0] / DIN;              // 100000
    const int E = in_sizes[2];                    // 3200000
    const int* row32 = ei;
    const int* col32 = ei + E;
    const int nblk = (E + EPB - 1) / EPB;         // 782
    const int NB   = (N + CPB - 1) / CPB;         // 782
    const int nbk  = (N + NPB - 1) / NPB;         // 98

    char* w = (char*)d_ws;
    size_t off = 0;
    auto alloc = [&](size_t bytes) -> void* {
        void* p = w + off;
        off = (off + bytes + 255) & ~(size_t)255;
        return p;
    };
    int*  T      = (int*)alloc((size_t)NB * 4);
    int*  bStart = (int*)alloc((size_t)(NB + 1) * 4);
    int*  H      = (int*)alloc((size_t)nblk * NB * 4);
    int*  O      = (int*)alloc((size_t)nblk * NB * 4);
    int*  start  = (int*)alloc((size_t)(N + 1) * 4);
    float* dis   = (float*)alloc((size_t)N * 4);
    float* selfw = (float*)alloc((size_t)N * 4);
    int*  HD     = (int*)alloc((size_t)nbk * 256 * 4);
    int*  OD     = (int*)alloc((size_t)nbk * 256 * 4);
    int*  binStart = (int*)alloc(257 * 4);
    int*  perm   = (int*)alloc((size_t)N * 4);
    int*  iperm  = (int*)alloc((size_t)N * 4);
    int4* nodepack = (int4*)alloc((size_t)N * 16);
    int2* bins   = (int2*)alloc(((size_t)E + EPAD) * 8); // pad
    float* hwA   = (float*)alloc((size_t)N * HID * 4);
    float* hwB   = (float*)alloc((size_t)N * HID * 4);
    (void)ws_size;

    hipMemsetAsync(T, 0, (size_t)NB * 4, stream);

    int gridN1 = (N + 255) / 256;

    s1_hist<<<nblk, 256, 0, stream>>>(col32, H, T, E, N, NB);
    s2b_scan<<<1, 1024, 0, stream>>>(T, bStart, NB);
    s2c_scan<<<(NB * 64 + 255) / 256, 256, 0, stream>>>(H, bStart, O, NB, nblk);
    s3_bin<<<nblk, 256, 0, stream>>>(row32, col32, ew, O, bins, E, N, NB);
    s4_sort<<<NB, 256, 0, stream>>>(bStart, bins, start, dis, selfw, E, N);
    pd1_hist<<<nbk, 256, 0, stream>>>(start, HD, N);
    pd2a_scan<<<1, 256, 0, stream>>>(HD, binStart, nbk);
    pd2b_off<<<64, 256, 0, stream>>>(HD, binStart, OD, nbk);
    pd3_fill<<<nbk, 256, 0, stream>>>(start, OD, perm, N);
    pd4_inv<<<gridN1, 256, 0, stream>>>(perm, iperm, N);
    p4_pack<<<gridN1, 256, 0, stream>>>(perm, start, selfw, nodepack, N);
    s7_norm<<<NB, 256, 0, stream>>>(bStart, bins, dis, iperm, E);
    int2* epack = bins;

    int gridN4 = (N * 4 + 255) / 256;

    gemm0<<<gridN4, 256, 0, stream>>>(x, W0, hwA, perm, N, DIN);

    // 12 fused agg+gemm layers: agg_i (bias_i) + gemm_{i+1}
    float* bufs[2] = {hwA, hwB};
    for (int i = 0; i < 11; ++i) {
        const float* bias = (i == 0) ? b0 : bmid + (size_t)(i - 1) * HID;
        const float* Wn   = Wmid + (size_t)i * HID * HID;
        agg_fused<4><<<gridN4, 256, 0, stream>>>(bufs[i & 1], epack, nodepack,
                                                 bias, Wn, bufs[(i + 1) & 1], N);
    }
    // i = 11: bias = bmid[10], next gemm = Wlast (16 -> 12)
    agg_fused<3><<<gridN4, 256, 0, stream>>>(bufs[1], epack, nodepack,
                                             bmid + (size_t)10 * HID, Wlast,
                                             bufs[0], N);
    // final agg over 12-wide hw, bias blast -> d_out (original order)
    agg_last<<<gridN4, 256, 0, stream>>>(bufs[0], epack, nodepack, blast,
                                         (float*)d_out, N);
}